// Round 8
// baseline (293.353 us; speedup 1.0000x reference)
//
#include <hip/hip_runtime.h>
#include <hip/hip_bf16.h>

#define A_N   2048
#define D_N   64
#define FL_N  12
#define KTOT  (A_N * FL_N)          // 24576
#define S_SPLIT 32
#define KCHUNK 768                  // cols per kc-chunk (KTOT/32)
#define BKN   128                   // k per 64-row tile
#define NBK   6                     // KCHUNK/BKN

// Fragment-linear tile layout (16 KB = 64 rows x 128 k bf16):
//   byte = (fw*4 + ks)*1024 + (grp*16 + l15)*16 + kin*2
//   where row = fw*16 + l15, k = ks*32 + grp*8 + kin.
// A wave's MFMA fragment load = 64 lanes x 16 B contiguous = 1 KB linear.

typedef __attribute__((ext_vector_type(8))) short bf16x8;  // 8 bf16 = 4 VGPRs
typedef __attribute__((ext_vector_type(4))) short bf16x4;  // 8 B
typedef __attribute__((ext_vector_type(4))) float f32x4;

__device__ __forceinline__ short f2bf(float f) {
  union { __hip_bfloat16 b; short s; } u;
  u.b = __float2bfloat16(f);
  return u.s;
}

// ---------- fused setup + conn conversion (fragment-linear tiles) ----------
__global__ void k_setup_cvt(const float* __restrict__ pf0, const float* __restrict__ bf0,
                            const float* __restrict__ pf1, const float* __restrict__ bf1,
                            const float* __restrict__ bp, const float* __restrict__ x,
                            const float* __restrict__ conn,
                            short* __restrict__ P2_0, short* __restrict__ P2_1,
                            float* __restrict__ bond0, float* __restrict__ bond1,
                            short* __restrict__ xb, short* __restrict__ connb2) {
  int b = blockIdx.x, t = threadIdx.x;
  if (b >= 768) {
    size_t slot = (size_t)(b - 768) * 256 + t;        // < 1048576
#pragma unroll
    for (int cc = 0; cc < 6; ++cc) {
      size_t i = (slot + (size_t)cc * 1048576) * 8;   // covers 50331648 floats exactly
      f32x4 a0 = __builtin_nontemporal_load((const f32x4*)(conn + i));
      f32x4 a1 = __builtin_nontemporal_load((const f32x4*)(conn + i + 4));
      bf16x8 v;
      v[0]=f2bf(a0[0]); v[1]=f2bf(a0[1]); v[2]=f2bf(a0[2]); v[3]=f2bf(a0[3]);
      v[4]=f2bf(a1[0]); v[5]=f2bf(a1[1]); v[6]=f2bf(a1[2]); v[7]=f2bf(a1[3]);
      int a = (int)(i / KTOT), c = (int)(i % KTOT);   // c is 8-aligned
      int rt64 = a >> 6, r64 = a & 63;
      int w_ = r64 >> 4, l15_ = r64 & 15;
      int kc = c / KCHUNK; int krem = c - kc * KCHUNK;
      int bk = krem >> 7, kk = krem & 127;
      int ks = kk >> 5, g2 = (kk >> 3) & 3;
      size_t dst = (((size_t)((rt64 * S_SPLIT + kc) * NBK + bk)) << 14)
                   + ((w_ * 4 + ks) << 10) + ((g2 * 16 + l15_) << 4);
      *(bf16x8*)((char*)connb2 + dst) = v;
    }
    return;
  }
  if (b < 192) {
    int idx = b * 256 + t;                       // < 49152
    int f = (idx >> 6) % FL_N;
    int o = idx / (D_N * FL_N);
    P2_0[idx] = f2bf(pf0[idx] * bf0[(o * FL_N + f) * 3]);
    P2_1[idx] = f2bf(pf1[idx] * bf1[(o * FL_N + f) * 3]);
  } else if (b < 704) {
    int o = t & 63;
    int a = (b - 192) * 4 + (t >> 6);
    float s0 = 0.f, s1 = 0.f;
#pragma unroll
    for (int f = 0; f < FL_N; ++f) {
      float c0 = bp[(a * FL_N + f) * 2 + 0];
      float c1 = bp[(a * FL_N + f) * 2 + 1];
      s0 += c0 * bf0[(o * FL_N + f) * 3 + 1] + c1 * bf0[(o * FL_N + f) * 3 + 2];
      s1 += c0 * bf1[(o * FL_N + f) * 3 + 1] + c1 * bf1[(o * FL_N + f) * 3 + 2];
    }
    bond0[a * D_N + o] = s0;
    bond1[a * D_N + o] = s1;
  } else {
    int i = ((b - 704) * 256 + t) * 8;
    f32x4 a0 = *(const f32x4*)(x + i);
    f32x4 a1 = *(const f32x4*)(x + i + 4);
    bf16x8 v;
    v[0]=f2bf(a0[0]); v[1]=f2bf(a0[1]); v[2]=f2bf(a0[2]); v[3]=f2bf(a0[3]);
    v[4]=f2bf(a1[0]); v[5]=f2bf(a1[1]); v[6]=f2bf(a1[2]); v[7]=f2bf(a1[3]);
    *(bf16x8*)(xb + i) = v;
  }
}

// ---------- Bt prep ----------
// Bt2: slab(kc,bk) = 16 KB fragment-linear, rows are o (0..63), k = kk (0..127).
__device__ __forceinline__ void prep_body(bf16x8 h0, bf16x8 h1,
                                          const short* __restrict__ P2,
                                          short* __restrict__ Bt2,
                                          int k0, int lane, int w) {
  int l15 = lane & 15, grp = lane >> 4;
  const short* prow = P2 + (w * 16 + l15) * (FL_N * D_N) + grp * 8;
  f32x4 acc[FL_N];
#pragma unroll
  for (int f = 0; f < FL_N; ++f) {
    bf16x8 p0 = *(const bf16x8*)(prow + f * D_N);
    bf16x8 p1 = *(const bf16x8*)(prow + f * D_N + 32);
    f32x4 c = {0.f, 0.f, 0.f, 0.f};
    c = __builtin_amdgcn_mfma_f32_16x16x32_bf16(p0, h0, c, 0, 0, 0);
    c = __builtin_amdgcn_mfma_f32_16x16x32_bf16(p1, h1, c, 0, 0, 0);
    acc[f] = c;
  }
  // D layout: row(o) = w*16 + grp*4 + r, col(katom) = k0 + l15
#pragma unroll
  for (int r = 0; r < 4; ++r) {
    int o = w * 16 + grp * 4 + r;
    int katom = k0 + l15;
    int j = o >> 4, lo = o & 15;
#pragma unroll
    for (int f = 0; f < FL_N; ++f) {
      int c = katom * FL_N + f;
      int kc = c / KCHUNK;
      int krem = c - kc * KCHUNK;
      int bk = krem >> 7, kk = krem & 127;
      int ks = kk >> 5, g2 = (kk >> 3) & 3, kin = kk & 7;
      *(short*)((char*)Bt2 + (((size_t)(kc * NBK + bk)) << 14)
                + ((j * 4 + ks) << 10) + ((g2 * 16 + lo) << 4) + (kin << 1))
          = f2bf(acc[f][r]);
    }
  }
}

// prep for conv0: h = xb
__global__ void k_prep0(const short* __restrict__ xb, const short* __restrict__ P2,
                        short* __restrict__ Bt2) {
  int lane = threadIdx.x & 63, w = threadIdx.x >> 6;
  int l15 = lane & 15, grp = lane >> 4;
  int k0 = blockIdx.x * 16;
  const short* hrow = xb + (k0 + l15) * D_N + grp * 8;
  bf16x8 h0 = *(const bf16x8*)(hrow);
  bf16x8 h1 = *(const bf16x8*)(hrow + 32);
  prep_body(h0, h1, P2, Bt2, k0, lane, w);
}

// prep conv c>0: reduce prev partials for 16 atoms, bond(+x)+relu, LDS, MFMA-prep.
template <int ADDX>
__global__ void k_prep_r(const float* __restrict__ part, const float* __restrict__ bond,
                         const float* __restrict__ x, const short* __restrict__ P2,
                         short* __restrict__ Bt2) {
  __shared__ short hsh[16 * 64];
  int t = threadIdx.x;
  int k0 = blockIdx.x * 16;
  int r  = t >> 4;            // 0..15 local row
  int d0 = (t & 15) * 4;      // 4 floats per thread
  size_t base = (size_t)(k0 + r) * D_N + d0;
  f32x4 s = *(const f32x4*)(bond + base);
#pragma unroll
  for (int si = 0; si < S_SPLIT; ++si) {
    f32x4 p = *(const f32x4*)(part + (size_t)si * (A_N * D_N) + base);
    s[0] += p[0]; s[1] += p[1]; s[2] += p[2]; s[3] += p[3];
  }
  if (ADDX) {
    f32x4 xv = *(const f32x4*)(x + base);
    s[0] += xv[0]; s[1] += xv[1]; s[2] += xv[2]; s[3] += xv[3];
  }
  bf16x4 hv;
  hv[0] = f2bf(fmaxf(s[0], 0.f)); hv[1] = f2bf(fmaxf(s[1], 0.f));
  hv[2] = f2bf(fmaxf(s[2], 0.f)); hv[3] = f2bf(fmaxf(s[3], 0.f));
  *(bf16x4*)(&hsh[r * 64 + d0]) = hv;
  __syncthreads();
  int lane = t & 63, w = t >> 6, l15 = lane & 15, grp = lane >> 4;
  bf16x8 h0 = *(const bf16x8*)(&hsh[l15 * 64 + grp * 8]);
  bf16x8 h1 = *(const bf16x8*)(&hsh[l15 * 64 + grp * 8 + 32]);
  prep_body(h0, h1, P2, Bt2, k0, lane, w);
}

// ---------- big GEMM: no LDS, no barriers, fragment-direct loads ----------
// Block (rt 0..15, kc 0..31) = 128 rows x 768 k; wave w owns 32 rows
// (64-row tile rt*2+(w>>1), halves fw=(w&1)*2 + rg). Per bk: 8 NT A-frag loads,
// 16 B-frag loads (wave-identical across 4 waves -> L1 broadcast), 32 MFMA.
// grid 512 = 2 blocks/CU, 8 waves/CU, pure dataflow.
template <int C>
__global__ __launch_bounds__(256, 2) void k_gemm(const short* __restrict__ connb2,
                                                 const short* __restrict__ Bt2,
                                                 float* __restrict__ part) {
  int t = threadIdx.x, lane = t & 63, w = t >> 6, l15 = lane & 15, grp = lane >> 4;
  int bid = blockIdx.x;
  int rt = bid & 15, kc = bid >> 4;
  int rowtile = rt * 2 + (w >> 1);            // 64-row tile 0..31
  const int fwb = (w & 1) * 2;

  const char* Abase = (const char*)connb2
      + (((size_t)((rowtile * S_SPLIT + kc) * NBK)) << 14) + (lane << 4);
  const char* Bbase = (const char*)Bt2
      + (((size_t)(kc * NBK)) << 14) + (lane << 4);

  f32x4 acc[2][4] = {};

#pragma unroll 2
  for (int bk = 0; bk < NBK; ++bk) {
    const char* At = Abase + ((size_t)bk << 14);
    const char* Bt = Bbase + ((size_t)bk << 14);
    bf16x8 a[2][4], bfr[4][4];
#pragma unroll
    for (int rg = 0; rg < 2; ++rg)
#pragma unroll
      for (int ks = 0; ks < 4; ++ks)
        a[rg][ks] = __builtin_nontemporal_load(
            (const bf16x8*)(At + (((fwb + rg) * 4 + ks) << 10)));
#pragma unroll
    for (int j = 0; j < 4; ++j)
#pragma unroll
      for (int ks = 0; ks < 4; ++ks)
        bfr[j][ks] = *(const bf16x8*)(Bt + ((j * 4 + ks) << 10));
#pragma unroll
    for (int rg = 0; rg < 2; ++rg)
#pragma unroll
      for (int j = 0; j < 4; ++j)
#pragma unroll
        for (int ks = 0; ks < 4; ++ks)
          acc[rg][j] = __builtin_amdgcn_mfma_f32_16x16x32_bf16(
              a[rg][ks], bfr[j][ks], acc[rg][j], 0, 0, 0);
  }

  float* p = part + (size_t)kc * (A_N * D_N);
#pragma unroll
  for (int rg = 0; rg < 2; ++rg) {
    int rbase = rowtile * 64 + (w & 1) * 32 + rg * 16 + grp * 4;
#pragma unroll
    for (int r = 0; r < 4; ++r) {
      float* pr = p + (size_t)(rbase + r) * D_N + l15;
      pr[0]  = acc[rg][0][r];
      pr[16] = acc[rg][1][r];
      pr[32] = acc[rg][2][r];
      pr[48] = acc[rg][3][r];
    }
  }
}

// ---------- final reduce -> f32 out ----------
__global__ void k_final(const float* __restrict__ part, const float* __restrict__ bond,
                        const float* __restrict__ x, float* __restrict__ out) {
  int i = blockIdx.x * 256 + threadIdx.x;   // 131072 total
  float s = bond[i];
#pragma unroll
  for (int si = 0; si < S_SPLIT; ++si) s += part[(size_t)si * (A_N * D_N) + i];
  out[i] = fmaxf(s + x[i], 0.f);
}

// ---------- launch ----------
extern "C" void kernel_launch(void* const* d_in, const int* in_sizes, int n_in,
                              void* d_out, int out_size, void* d_ws, size_t ws_size,
                              hipStream_t stream) {
  const float* x    = (const float*)d_in[0];
  const float* conn = (const float*)d_in[1];
  const float* bprp = (const float*)d_in[2];
  const float* pf0  = (const float*)d_in[3];
  const float* bf0  = (const float*)d_in[4];
  const float* pf1  = (const float*)d_in[5];
  const float* bf1  = (const float*)d_in[6];
  float* out = (float*)d_out;

  char* ws = (char*)d_ws;
  size_t off = 0;
  short* connb2 = (short*)(ws + off); off += (size_t)A_N * KTOT * 2;           // 100.7 MB
  short* Bt2    = (short*)(ws + off); off += (size_t)D_N * KTOT * 2;           // 3 MB
  float* part   = (float*)(ws + off); off += (size_t)S_SPLIT * A_N * D_N * 4;  // 16.8 MB
  short* xb     = (short*)(ws + off); off += (size_t)A_N * D_N * 2;
  float* bond0  = (float*)(ws + off); off += (size_t)A_N * D_N * 4;
  float* bond1  = (float*)(ws + off); off += (size_t)A_N * D_N * 4;
  short* P2_0   = (short*)(ws + off); off += (size_t)D_N * FL_N * D_N * 2;
  short* P2_1   = (short*)(ws + off); off += (size_t)D_N * FL_N * D_N * 2;

  k_setup_cvt<<<4864, 256, 0, stream>>>(pf0, bf0, pf1, bf1, bprp, x, conn,
                                        P2_0, P2_1, bond0, bond1, xb, connb2);

  // conv0: h = x
  k_prep0<<<128, 256, 0, stream>>>(xb, P2_0, Bt2);
  k_gemm<0><<<512, 256, 0, stream>>>(connb2, Bt2, part);

  // conv1: h1 = relu(conv0); bond0; P2_0
  k_prep_r<0><<<128, 256, 0, stream>>>(part, bond0, x, P2_0, Bt2);
  k_gemm<1><<<512, 256, 0, stream>>>(connb2, Bt2, part);

  // conv2: h2 = relu(conv1 + x); bond0; P2_1
  k_prep_r<1><<<128, 256, 0, stream>>>(part, bond0, x, P2_1, Bt2);
  k_gemm<2><<<512, 256, 0, stream>>>(connb2, Bt2, part);

  // conv3: h3 = relu(conv2); bond1; P2_1
  k_prep_r<0><<<128, 256, 0, stream>>>(part, bond1, x, P2_1, Bt2);
  k_gemm<3><<<512, 256, 0, stream>>>(connb2, Bt2, part);

  // out = relu(conv3 + bond1 + x)
  k_final<<<512, 256, 0, stream>>>(part, bond1, x, out);
}

// Round 9
// 183.126 us; speedup vs baseline: 1.6019x; 1.6019x over previous
//
#include <hip/hip_runtime.h>
#include <hip/hip_bf16.h>

#define A_N   2048
#define D_N   64
#define FL_N  12
#define KTOT  (A_N * FL_N)          // 24576
#define S_SPLIT 16
#define KCHUNK 1536                 // cols per kc-chunk (KTOT/16)
#define BKN   128                   // k per staged tile
#define NBK   12                    // KCHUNK/BKN
#define TILE_B 16384                // 64 rows * 128 k * 2B

typedef __attribute__((ext_vector_type(8))) short bf16x8;  // 8 bf16 = 4 VGPRs
typedef __attribute__((ext_vector_type(4))) short bf16x4;  // 8 B
typedef __attribute__((ext_vector_type(4))) float f32x4;

__device__ __forceinline__ short f2bf(float f) {
  union { __hip_bfloat16 b; short s; } u;
  u.b = __float2bfloat16(f);
  return u.s;
}

// ---------- fused setup + conn conversion (tiled layout) ----------
// connb2 layout: tile(rt,kc,bk) = contiguous 16 KB = [row r 0..63][k 0..127] bf16.
__global__ void k_setup_cvt(const float* __restrict__ pf0, const float* __restrict__ bf0,
                            const float* __restrict__ pf1, const float* __restrict__ bf1,
                            const float* __restrict__ bp, const float* __restrict__ x,
                            const float* __restrict__ conn,
                            short* __restrict__ P2_0, short* __restrict__ P2_1,
                            float* __restrict__ bond0, float* __restrict__ bond1,
                            short* __restrict__ xb, short* __restrict__ connb2) {
  int b = blockIdx.x, t = threadIdx.x;
  if (b >= 768) {
    size_t slot = (size_t)(b - 768) * 256 + t;        // < 1048576
#pragma unroll
    for (int cc = 0; cc < 6; ++cc) {
      size_t i = (slot + (size_t)cc * 1048576) * 8;   // covers 50331648 floats exactly
      f32x4 a0 = __builtin_nontemporal_load((const f32x4*)(conn + i));
      f32x4 a1 = __builtin_nontemporal_load((const f32x4*)(conn + i + 4));
      bf16x8 v;
      v[0]=f2bf(a0[0]); v[1]=f2bf(a0[1]); v[2]=f2bf(a0[2]); v[3]=f2bf(a0[3]);
      v[4]=f2bf(a1[0]); v[5]=f2bf(a1[1]); v[6]=f2bf(a1[2]); v[7]=f2bf(a1[3]);
      int a = (int)(i / KTOT), c = (int)(i % KTOT);   // k = c&127 multiple of 8
      int rt = a >> 6, r = a & 63;
      int kc = c / KCHUNK, rem = c % KCHUNK;
      int bk = rem >> 7, k = rem & 127;
      size_t dst = ((size_t)((rt * 16 + kc) * NBK + bk) << 14) + (r << 8) + (k << 1);
      *(bf16x8*)((char*)connb2 + dst) = v;
    }
    return;
  }
  if (b < 192) {
    int idx = b * 256 + t;                       // < 49152
    int f = (idx >> 6) % FL_N;
    int o = idx / (D_N * FL_N);
    P2_0[idx] = f2bf(pf0[idx] * bf0[(o * FL_N + f) * 3]);
    P2_1[idx] = f2bf(pf1[idx] * bf1[(o * FL_N + f) * 3]);
  } else if (b < 704) {
    int o = t & 63;
    int a = (b - 192) * 4 + (t >> 6);
    float s0 = 0.f, s1 = 0.f;
#pragma unroll
    for (int f = 0; f < FL_N; ++f) {
      float c0 = bp[(a * FL_N + f) * 2 + 0];
      float c1 = bp[(a * FL_N + f) * 2 + 1];
      s0 += c0 * bf0[(o * FL_N + f) * 3 + 1] + c1 * bf0[(o * FL_N + f) * 3 + 2];
      s1 += c0 * bf1[(o * FL_N + f) * 3 + 1] + c1 * bf1[(o * FL_N + f) * 3 + 2];
    }
    bond0[a * D_N + o] = s0;
    bond1[a * D_N + o] = s1;
  } else {
    int i = ((b - 704) * 256 + t) * 8;
    f32x4 a0 = *(const f32x4*)(x + i);
    f32x4 a1 = *(const f32x4*)(x + i + 4);
    bf16x8 v;
    v[0]=f2bf(a0[0]); v[1]=f2bf(a0[1]); v[2]=f2bf(a0[2]); v[3]=f2bf(a0[3]);
    v[4]=f2bf(a1[0]); v[5]=f2bf(a1[1]); v[6]=f2bf(a1[2]); v[7]=f2bf(a1[3]);
    *(bf16x8*)(xb + i) = v;
  }
}

// ---------- Bt prep ----------
// Bt2 layout: slab(kc,bk) = contiguous 16 KB = [o 0..63][k 0..127] bf16.
__device__ __forceinline__ void prep_body(bf16x8 h0, bf16x8 h1,
                                          const short* __restrict__ P2,
                                          short* __restrict__ Bt2,
                                          int k0, int lane, int w) {
  int l15 = lane & 15, grp = lane >> 4;
  const short* prow = P2 + (w * 16 + l15) * (FL_N * D_N) + grp * 8;
  f32x4 acc[FL_N];
#pragma unroll
  for (int f = 0; f < FL_N; ++f) {
    bf16x8 p0 = *(const bf16x8*)(prow + f * D_N);
    bf16x8 p1 = *(const bf16x8*)(prow + f * D_N + 32);
    f32x4 c = {0.f, 0.f, 0.f, 0.f};
    c = __builtin_amdgcn_mfma_f32_16x16x32_bf16(p0, h0, c, 0, 0, 0);
    c = __builtin_amdgcn_mfma_f32_16x16x32_bf16(p1, h1, c, 0, 0, 0);
    acc[f] = c;
  }
  // D layout: row(o) = grp*4 + r (+w*16), col(katom) = l15 (+k0)
#pragma unroll
  for (int r = 0; r < 4; ++r) {
    int o = w * 16 + grp * 4 + r;
    int katom = k0 + l15;
#pragma unroll
    for (int f = 0; f < FL_N; ++f) {
      int c = katom * FL_N + f;
      int kc = c / KCHUNK, rem = c % KCHUNK;
      int bk = rem >> 7, k = rem & 127;
      *(short*)((char*)Bt2 + ((size_t)(kc * NBK + bk) << 14) + (o << 8) + (k << 1))
          = f2bf(acc[f][r]);
    }
  }
}

// prep for conv0: h = xb
__global__ void k_prep0(const short* __restrict__ xb, const short* __restrict__ P2,
                        short* __restrict__ Bt2) {
  int lane = threadIdx.x & 63, w = threadIdx.x >> 6;
  int l15 = lane & 15, grp = lane >> 4;
  int k0 = blockIdx.x * 16;
  const short* hrow = xb + (k0 + l15) * D_N + grp * 8;
  bf16x8 h0 = *(const bf16x8*)(hrow);
  bf16x8 h1 = *(const bf16x8*)(hrow + 32);
  prep_body(h0, h1, P2, Bt2, k0, lane, w);
}

// prep conv c>0: reduce prev partials for 16 atoms, bond(+x)+relu, LDS, MFMA-prep.
template <int ADDX>
__global__ void k_prep_r(const float* __restrict__ part, const float* __restrict__ bond,
                         const float* __restrict__ x, const short* __restrict__ P2,
                         short* __restrict__ Bt2) {
  __shared__ short hsh[16 * 64];
  int t = threadIdx.x;
  int k0 = blockIdx.x * 16;
  int r  = t >> 4;            // 0..15 local row
  int d0 = (t & 15) * 4;      // 4 floats per thread
  size_t base = (size_t)(k0 + r) * D_N + d0;
  f32x4 s = *(const f32x4*)(bond + base);
#pragma unroll
  for (int si = 0; si < S_SPLIT; ++si) {
    f32x4 p = *(const f32x4*)(part + (size_t)si * (A_N * D_N) + base);
    s[0] += p[0]; s[1] += p[1]; s[2] += p[2]; s[3] += p[3];
  }
  if (ADDX) {
    f32x4 xv = *(const f32x4*)(x + base);
    s[0] += xv[0]; s[1] += xv[1]; s[2] += xv[2]; s[3] += xv[3];
  }
  bf16x4 hv;
  hv[0] = f2bf(fmaxf(s[0], 0.f)); hv[1] = f2bf(fmaxf(s[1], 0.f));
  hv[2] = f2bf(fmaxf(s[2], 0.f)); hv[3] = f2bf(fmaxf(s[3], 0.f));
  *(bf16x4*)(&hsh[r * 64 + d0]) = hv;
  __syncthreads();
  int lane = t & 63, w = t >> 6, l15 = lane & 15, grp = lane >> 4;
  bf16x8 h0 = *(const bf16x8*)(&hsh[l15 * 64 + grp * 8]);
  bf16x8 h1 = *(const bf16x8*)(&hsh[l15 * 64 + grp * 8 + 32]);
  prep_body(h0, h1, P2, Bt2, k0, lane, w);
}

// ---------- big GEMM: LDS-staged, DEPTH-2 register prefetch, XOR-swizzled ----------
// Block (rt,kc): 64 rows x 1536 k; 12 bk-steps of 64x128 A-tile + 64x128 Bt-slab.
// Reg set s holds tile T with T%2==s; LDS buf b holds tile T with T%2==b.
// Iter bk: issue loads T(bk+2) -> set[bk&1]; compute lds[bk&1];
//          ds_write lds[(bk+1)&1] <- set[(bk+1)&1] (auto counted vmcnt(8)); barrier.
template <int C>
__global__ __launch_bounds__(256, 2) void k_gemm(const short* __restrict__ connb2,
                                                 const short* __restrict__ Bt2,
                                                 float* __restrict__ part) {
  __shared__ short lA[2][8192];   // 16 KB each buf: [row 64][k 128] swizzled
  __shared__ short lB[2][8192];
  int t = threadIdx.x;
  int lane = t & 63, w = t >> 6, l15 = lane & 15, grp = lane >> 4;
  int rt = blockIdx.x, kc = blockIdx.y;

  const char* Ab = (const char*)connb2 + (((size_t)(rt * 16 + kc) * NBK) << 14);
  const char* Bb = (const char*)Bt2 + (((size_t)kc * NBK) << 14);

  // staging: thread t, round q -> tile chunk j = q*256+t (16 B); LDS XOR-swizzle
  int ldsoff[4];
#pragma unroll
  for (int q = 0; q < 4; ++q) {
    int j = q * 256 + t;
    int row = j >> 4, cw = j & 15;
    ldsoff[q] = (row << 8) + ((cw << 4) ^ ((row & 7) << 4));
  }

  bf16x8 ra[2][4], rb[2][4];

  // prologue: T0 -> set0, T1 -> set1; stage T0 into lds[0]
#pragma unroll
  for (int q = 0; q < 4; ++q) {
    ra[0][q] = *(const bf16x8*)(Ab + q * 4096 + t * 16);
    rb[0][q] = *(const bf16x8*)(Bb + q * 4096 + t * 16);
  }
#pragma unroll
  for (int q = 0; q < 4; ++q) {
    ra[1][q] = *(const bf16x8*)(Ab + TILE_B + q * 4096 + t * 16);
    rb[1][q] = *(const bf16x8*)(Bb + TILE_B + q * 4096 + t * 16);
  }
#pragma unroll
  for (int q = 0; q < 4; ++q) {
    *(bf16x8*)((char*)&lA[0][0] + ldsoff[q]) = ra[0][q];
    *(bf16x8*)((char*)&lB[0][0] + ldsoff[q]) = rb[0][q];
  }
  __syncthreads();

  f32x4 acc0 = {0,0,0,0}, acc1 = {0,0,0,0}, acc2 = {0,0,0,0}, acc3 = {0,0,0,0};
  const int arow = (w * 16 + l15) << 8;     // A row byte base
  const int brow = l15 << 8;                // B row byte base (within o-tile)
  const int key  = (l15 & 7) << 4;

#pragma unroll
  for (int bk = 0; bk < NBK; ++bk) {
    const int cur = bk & 1;
    const int nxt = cur ^ 1;
    if (bk + 2 < NBK) {                     // issue loads for tile bk+2 (depth-2)
      const char* An = Ab + (size_t)(bk + 2) * TILE_B;
      const char* Bn = Bb + (size_t)(bk + 2) * TILE_B;
#pragma unroll
      for (int q = 0; q < 4; ++q) {
        ra[cur][q] = *(const bf16x8*)(An + q * 4096 + t * 16);
        rb[cur][q] = *(const bf16x8*)(Bn + q * 4096 + t * 16);
      }
    }
    const char* la = (const char*)&lA[cur][0];
    const char* lb = (const char*)&lB[cur][0];
#pragma unroll
    for (int ks = 0; ks < 4; ++ks) {
      const int cb = ((ks << 6) + (grp << 4)) ^ key;
      bf16x8 af = *(const bf16x8*)(la + arow + cb);
      bf16x8 b0 = *(const bf16x8*)(lb + brow + cb);
      bf16x8 b1 = *(const bf16x8*)(lb + 4096 + brow + cb);
      bf16x8 b2 = *(const bf16x8*)(lb + 8192 + brow + cb);
      bf16x8 b3 = *(const bf16x8*)(lb + 12288 + brow + cb);
      acc0 = __builtin_amdgcn_mfma_f32_16x16x32_bf16(af, b0, acc0, 0, 0, 0);
      acc1 = __builtin_amdgcn_mfma_f32_16x16x32_bf16(af, b1, acc1, 0, 0, 0);
      acc2 = __builtin_amdgcn_mfma_f32_16x16x32_bf16(af, b2, acc2, 0, 0, 0);
      acc3 = __builtin_amdgcn_mfma_f32_16x16x32_bf16(af, b3, acc3, 0, 0, 0);
    }
    if (bk + 1 < NBK) {                     // stage tile bk+1 (loaded last iter)
#pragma unroll
      for (int q = 0; q < 4; ++q) {
        *(bf16x8*)((char*)&lA[nxt][0] + ldsoff[q]) = ra[nxt][q];
        *(bf16x8*)((char*)&lB[nxt][0] + ldsoff[q]) = rb[nxt][q];
      }
      __syncthreads();
    }
  }

  float* p = part + (size_t)kc * (A_N * D_N);
  int rbase = rt * 64 + w * 16 + grp * 4;
#pragma unroll
  for (int r = 0; r < 4; ++r) {
    float* pr = p + (size_t)(rbase + r) * D_N + l15;
    pr[0]  = acc0[r];
    pr[16] = acc1[r];
    pr[32] = acc2[r];
    pr[48] = acc3[r];
  }
}

// ---------- final reduce -> f32 out ----------
__global__ void k_final(const float* __restrict__ part, const float* __restrict__ bond,
                        const float* __restrict__ x, float* __restrict__ out) {
  int i = blockIdx.x * 256 + threadIdx.x;   // 131072 total
  float s = bond[i];
#pragma unroll
  for (int si = 0; si < S_SPLIT; ++si) s += part[(size_t)si * (A_N * D_N) + i];
  out[i] = fmaxf(s + x[i], 0.f);
}

// ---------- launch ----------
extern "C" void kernel_launch(void* const* d_in, const int* in_sizes, int n_in,
                              void* d_out, int out_size, void* d_ws, size_t ws_size,
                              hipStream_t stream) {
  const float* x    = (const float*)d_in[0];
  const float* conn = (const float*)d_in[1];
  const float* bprp = (const float*)d_in[2];
  const float* pf0  = (const float*)d_in[3];
  const float* bf0  = (const float*)d_in[4];
  const float* pf1  = (const float*)d_in[5];
  const float* bf1  = (const float*)d_in[6];
  float* out = (float*)d_out;

  char* ws = (char*)d_ws;
  size_t off = 0;
  short* connb2 = (short*)(ws + off); off += (size_t)A_N * KTOT * 2;           // 100.7 MB
  short* Bt2    = (short*)(ws + off); off += (size_t)D_N * KTOT * 2;           // 3 MB
  float* part   = (float*)(ws + off); off += (size_t)S_SPLIT * A_N * D_N * 4;  // 8.4 MB
  short* xb     = (short*)(ws + off); off += (size_t)A_N * D_N * 2;
  float* bond0  = (float*)(ws + off); off += (size_t)A_N * D_N * 4;
  float* bond1  = (float*)(ws + off); off += (size_t)A_N * D_N * 4;
  short* P2_0   = (short*)(ws + off); off += (size_t)D_N * FL_N * D_N * 2;
  short* P2_1   = (short*)(ws + off); off += (size_t)D_N * FL_N * D_N * 2;

  k_setup_cvt<<<4864, 256, 0, stream>>>(pf0, bf0, pf1, bf1, bprp, x, conn,
                                        P2_0, P2_1, bond0, bond1, xb, connb2);

  dim3 ggrid(32, 16);

  // conv0: h = x
  k_prep0<<<128, 256, 0, stream>>>(xb, P2_0, Bt2);
  k_gemm<0><<<ggrid, 256, 0, stream>>>(connb2, Bt2, part);

  // conv1: h1 = relu(conv0); bond0; P2_0
  k_prep_r<0><<<128, 256, 0, stream>>>(part, bond0, x, P2_0, Bt2);
  k_gemm<1><<<ggrid, 256, 0, stream>>>(connb2, Bt2, part);

  // conv2: h2 = relu(conv1 + x); bond0; P2_1
  k_prep_r<1><<<128, 256, 0, stream>>>(part, bond0, x, P2_1, Bt2);
  k_gemm<2><<<ggrid, 256, 0, stream>>>(connb2, Bt2, part);

  // conv3: h3 = relu(conv2); bond1; P2_1
  k_prep_r<0><<<128, 256, 0, stream>>>(part, bond1, x, P2_1, Bt2);
  k_gemm<3><<<ggrid, 256, 0, stream>>>(connb2, Bt2, part);

  // out = relu(conv3 + bond1 + x)
  k_final<<<512, 256, 0, stream>>>(part, bond1, x, out);
}